// Round 1
// baseline (8970.970 us; speedup 1.0000x reference)
//
#include <hip/hip_runtime.h>
#include <stdint.h>

#define C_   128
#define H_   128
#define W_   128
#define HW_  (128*128)

typedef unsigned short ushort_t;

__device__ __forceinline__ float bf2f(uint32_t u) {
    union { float f; uint32_t i; } v; v.i = u << 16; return v.f;
}
__device__ __forceinline__ uint32_t f2bf(float f) {
    union { float f; uint32_t i; } v; v.f = f;
    uint32_t u = v.i;
    uint32_t r = u + 0x7FFFu + ((u >> 16) & 1u);
    return r >> 16;  // RTNE bf16 bits in low 16
}
__device__ __forceinline__ void unp8(uint4 raw, float* d) {
    d[0] = bf2f(raw.x & 0xffffu); d[1] = bf2f(raw.x >> 16);
    d[2] = bf2f(raw.y & 0xffffu); d[3] = bf2f(raw.y >> 16);
    d[4] = bf2f(raw.z & 0xffffu); d[5] = bf2f(raw.z >> 16);
    d[6] = bf2f(raw.w & 0xffffu); d[7] = bf2f(raw.w >> 16);
}

// ---------------------------------------------------------------------------
// K1: q/k/v 1x1 convs, scatter directly into per-scale windowed layout (bf16).
// Windowed layout per scale s (patch p=2^lg, out=128>>lg, Ntok=4*out^2,
// D=32*p^2): elem offset = s*8388608 + ((b*Ntok + ntok)*D + dd),
// ntok = t*out^2 + oh*out + ow, dd = ((c_local<<lg)+ph)<<lg | pw.
// grid (128 rows, 16 imgs), block 256.
// ---------------------------------------------------------------------------
__global__ __launch_bounds__(256) void qkv_kernel(
    const float* __restrict__ x,
    const float* __restrict__ Wq, const float* __restrict__ bq,
    const float* __restrict__ Wk, const float* __restrict__ bk,
    const float* __restrict__ Wv, const float* __restrict__ bv,
    ushort_t* __restrict__ qw, ushort_t* __restrict__ kw, ushort_t* __restrict__ vw)
{
    __shared__ ushort_t xtb[128 * 128];   // [ci][px] bf16, 32 KB
    __shared__ float    wt[128 * 32];     // [ci][co_l] fp32, 16 KB
    const int h = blockIdx.x, img = blockIdx.y, tid = threadIdx.x;
    const float* xb = x + (size_t)img * C_ * HW_ + (size_t)h * W_;
    for (int i = tid; i < 4096; i += 256) {
        int ci = i >> 5, p4 = (i & 31) * 4;
        float4 xv = *(const float4*)&xb[(size_t)ci * HW_ + p4];
        uint2 pk;
        pk.x = f2bf(xv.x) | (f2bf(xv.y) << 16);
        pk.y = f2bf(xv.z) | (f2bf(xv.w) << 16);
        *(uint2*)&xtb[ci * 128 + p4] = pk;
    }
    const int b_ = img >> 2, t_ = img & 3;
    const int pxq = tid & 31, coq = tid >> 5;
    const int px0 = pxq * 4, col0 = coq * 4;

    for (int w3 = 0; w3 < 3; ++w3) {
        const float* Wp = (w3 == 0) ? Wq : ((w3 == 1) ? Wk : Wv);
        const float* bp = (w3 == 0) ? bq : ((w3 == 1) ? bk : bv);
        ushort_t*  outp = (w3 == 0) ? qw : ((w3 == 1) ? kw : vw);
        for (int cc = 0; cc < 4; ++cc) {
            __syncthreads();
            for (int i = tid; i < 4096; i += 256) {
                int col = i & 31, ci = i >> 5;
                wt[ci * 32 + col] = Wp[(cc * 32 + col) * 128 + ci];
            }
            __syncthreads();
            float acc[4][4];
            #pragma unroll
            for (int a = 0; a < 4; ++a) {
                float bb = bp[cc * 32 + col0 + a];
                #pragma unroll
                for (int e = 0; e < 4; ++e) acc[a][e] = bb;
            }
            #pragma unroll 4
            for (int ci = 0; ci < 128; ++ci) {
                uint2 xr = *(const uint2*)&xtb[ci * 128 + px0];
                float xv0 = bf2f(xr.x & 0xffffu), xv1 = bf2f(xr.x >> 16);
                float xv2 = bf2f(xr.y & 0xffffu), xv3 = bf2f(xr.y >> 16);
                float4 wv = *(const float4*)&wt[ci * 32 + col0];
                acc[0][0] += wv.x * xv0; acc[0][1] += wv.x * xv1; acc[0][2] += wv.x * xv2; acc[0][3] += wv.x * xv3;
                acc[1][0] += wv.y * xv0; acc[1][1] += wv.y * xv1; acc[1][2] += wv.y * xv2; acc[1][3] += wv.y * xv3;
                acc[2][0] += wv.z * xv0; acc[2][1] += wv.z * xv1; acc[2][2] += wv.z * xv2; acc[2][3] += wv.z * xv3;
                acc[3][0] += wv.w * xv0; acc[3][1] += wv.w * xv1; acc[3][2] += wv.w * xv2; acc[3][3] += wv.w * xv3;
            }
            // scatter to windowed layout (scale == cc since co-chunk = 32)
            const int lg  = 6 - cc;
            const int psz = 1 << lg, outn = 128 >> lg;
            const int Dd  = 32 << (2 * lg);
            const size_t base = (size_t)cc * 8388608u;
            const int oh = h >> lg, ph = h & (psz - 1);
            const int ow = px0 >> lg, pw0 = px0 & (psz - 1);
            const int ntok = t_ * outn * outn + oh * outn + ow;
            const size_t rowoff = base + ((size_t)(b_ * 4 * outn * outn + ntok)) * (size_t)Dd;
            #pragma unroll
            for (int a = 0; a < 4; ++a) {
                int c_local = col0 + a;
                int dd = (((c_local << lg) + ph) << lg) + pw0;
                uint2 pk;
                pk.x = f2bf(acc[a][0]) | (f2bf(acc[a][1]) << 16);
                pk.y = f2bf(acc[a][2]) | (f2bf(acc[a][3]) << 16);
                *(uint2*)&outp[rowoff + dd] = pk;
            }
        }
    }
}

// ---------------------------------------------------------------------------
// K2: scores = Q K^T / sqrt(D). 64x64 token tile, K chunk 32, optional K-split
// (ks_count blocks accumulate via atomicAdd; sc pre-zeroed by memset).
// grid (nb, nb, B*ks_count).
// ---------------------------------------------------------------------------
__global__ __launch_bounds__(256) void scores_kernel(
    const ushort_t* __restrict__ qw, const ushort_t* __restrict__ kw,
    float* __restrict__ sc, int lg, int ks_count)
{
    const int outn = 128 >> lg;
    const int n  = 4 * outn * outn;
    const int Dd = 32 << (2 * lg);
    const int scale = 6 - lg;
    const size_t base = (size_t)scale * 8388608u;
    const int b_ = blockIdx.z / ks_count;
    const int ks = blockIdx.z % ks_count;
    const int DdK = Dd / ks_count;
    const int n1b = blockIdx.x * 64, n2b = blockIdx.y * 64;
    const ushort_t* qb = qw + base + (size_t)b_ * (size_t)n * Dd;
    const ushort_t* kb = kw + base + (size_t)b_ * (size_t)n * Dd;
    __shared__ float qt[64 * 33];
    __shared__ float kt[64 * 33];
    const int tid = threadIdx.x;
    const int r0 = 4 * (tid >> 4), c0 = 4 * (tid & 15);
    float acc[4][4] = {};
    const int rld = tid >> 2, kb8 = (tid & 3) * 8;

    for (int k0 = ks * DdK; k0 < ks * DdK + DdK; k0 += 32) {
        __syncthreads();
        {
            float tmp[8];
            int n1 = n1b + rld;
            if (n1 < n) { uint4 raw = *(const uint4*)&qb[(size_t)n1 * Dd + k0 + kb8]; unp8(raw, tmp); }
            else { for (int j = 0; j < 8; ++j) tmp[j] = 0.f; }
            for (int j = 0; j < 8; ++j) qt[rld * 33 + kb8 + j] = tmp[j];
            int n2 = n2b + rld;
            if (n2 < n) { uint4 raw = *(const uint4*)&kb[(size_t)n2 * Dd + k0 + kb8]; unp8(raw, tmp); }
            else { for (int j = 0; j < 8; ++j) tmp[j] = 0.f; }
            for (int j = 0; j < 8; ++j) kt[rld * 33 + kb8 + j] = tmp[j];
        }
        __syncthreads();
        #pragma unroll 4
        for (int kk = 0; kk < 32; ++kk) {
            float qv[4], kv[4];
            #pragma unroll
            for (int a = 0; a < 4; ++a) { qv[a] = qt[(r0 + a) * 33 + kk]; kv[a] = kt[(c0 + a) * 33 + kk]; }
            #pragma unroll
            for (int a = 0; a < 4; ++a)
                #pragma unroll
                for (int e = 0; e < 4; ++e) acc[a][e] += qv[a] * kv[e];
        }
    }
    const float scl = rsqrtf((float)Dd);
    #pragma unroll
    for (int a = 0; a < 4; ++a) {
        int n1 = n1b + r0 + a;
        int n2 = n2b + c0;
        if (n1 < n && n2 < n) {
            size_t off = ((size_t)b_ * n + n1) * (size_t)n + n2;
            if (ks_count == 1) {
                float4 o = make_float4(acc[a][0] * scl, acc[a][1] * scl, acc[a][2] * scl, acc[a][3] * scl);
                *(float4*)&sc[off] = o;
            } else {
                #pragma unroll
                for (int e = 0; e < 4; ++e) atomicAdd(&sc[off + e], acc[a][e] * scl);
            }
        }
    }
}

// ---------------------------------------------------------------------------
// K3: row softmax in place. grid = B*n blocks, 256 threads, n <= 1024.
// ---------------------------------------------------------------------------
__global__ __launch_bounds__(256) void softmax_kernel(float* __restrict__ sc, int n)
{
    const int row = blockIdx.x;
    float* p = sc + (size_t)row * n;
    const int tid = threadIdx.x;
    float v[4];
    #pragma unroll
    for (int j = 0; j < 4; ++j) { int idx = tid + 256 * j; v[j] = (idx < n) ? p[idx] : -3.0e38f; }
    float m = fmaxf(fmaxf(v[0], v[1]), fmaxf(v[2], v[3]));
    #pragma unroll
    for (int off = 32; off >= 1; off >>= 1) m = fmaxf(m, __shfl_xor(m, off));
    __shared__ float red[4];
    const int wid = tid >> 6, lane = tid & 63;
    if (lane == 0) red[wid] = m;
    __syncthreads();
    m = fmaxf(fmaxf(red[0], red[1]), fmaxf(red[2], red[3]));
    float e[4]; float s = 0.f;
    #pragma unroll
    for (int j = 0; j < 4; ++j) { int idx = tid + 256 * j; e[j] = (idx < n) ? __expf(v[j] - m) : 0.f; s += e[j]; }
    #pragma unroll
    for (int off = 32; off >= 1; off >>= 1) s += __shfl_xor(s, off);
    __syncthreads();
    if (lane == 0) red[wid] = s;
    __syncthreads();
    s = red[0] + red[1] + red[2] + red[3];
    float inv = 1.0f / s;
    #pragma unroll
    for (int j = 0; j < 4; ++j) { int idx = tid + 256 * j; if (idx < n) p[idx] = e[j] * inv; }
}

// ---------------------------------------------------------------------------
// K4: y = P V, scatter to attn image (NCHW bf16). Tile 32 tokens x 128 dd.
// grid (Dd/128, ceil(n/32), B).
// ---------------------------------------------------------------------------
__global__ __launch_bounds__(256) void pv_kernel(
    const float* __restrict__ sc, const ushort_t* __restrict__ vw,
    ushort_t* __restrict__ attn, int lg)
{
    const int outn = 128 >> lg, psz = 1 << lg;
    const int n  = 4 * outn * outn;
    const int Dd = 32 << (2 * lg);
    const int scale = 6 - lg;
    const size_t base = (size_t)scale * 8388608u;
    const int b_ = blockIdx.z;
    const int dd0 = blockIdx.x * 128, n1b = blockIdx.y * 32;
    const ushort_t* vb = vw + base + (size_t)b_ * (size_t)n * Dd;
    const float* pb = sc + (size_t)b_ * n * n;
    __shared__ float pt[32 * 33];
    __shared__ float vt[32 * 132];
    const int tid = threadIdx.x;
    const int cq = tid & 31, rq = tid >> 5;
    const int r0 = 4 * rq, c0v = 4 * cq;
    float acc[4][4] = {};

    for (int m0 = 0; m0 < n; m0 += 32) {
        __syncthreads();
        for (int i = tid; i < 1024; i += 256) {
            int r = i >> 5, m = i & 31;
            int n1 = n1b + r, mm = m0 + m;
            pt[r * 33 + m] = (n1 < n && mm < n) ? pb[(size_t)n1 * n + mm] : 0.f;
        }
        for (int i = tid; i < 512; i += 256) {
            int m = i >> 4, c8 = (i & 15) * 8;
            int mm = m0 + m;
            float tmp[8];
            if (mm < n) { uint4 raw = *(const uint4*)&vb[(size_t)mm * Dd + dd0 + c8]; unp8(raw, tmp); }
            else { for (int j = 0; j < 8; ++j) tmp[j] = 0.f; }
            for (int j = 0; j < 8; ++j) vt[m * 132 + c8 + j] = tmp[j];
        }
        __syncthreads();
        #pragma unroll 4
        for (int m = 0; m < 32; ++m) {
            float pv4[4];
            #pragma unroll
            for (int j = 0; j < 4; ++j) pv4[j] = pt[(r0 + j) * 33 + m];
            float4 vv = *(const float4*)&vt[m * 132 + c0v];
            #pragma unroll
            for (int j = 0; j < 4; ++j) {
                acc[j][0] += pv4[j] * vv.x; acc[j][1] += pv4[j] * vv.y;
                acc[j][2] += pv4[j] * vv.z; acc[j][3] += pv4[j] * vv.w;
            }
        }
    }
    const int lgo = 7 - lg;
    const int dd = dd0 + c0v;
    const int c_local = dd >> (2 * lg);
    const int p2 = dd & (psz * psz - 1);
    const int ph = p2 >> lg, pw = p2 & (psz - 1);
    const int cch = scale * 32 + c_local;
    #pragma unroll
    for (int j = 0; j < 4; ++j) {
        int n1 = n1b + r0 + j;
        if (n1 >= n) continue;
        int t_ = n1 >> (2 * lgo);
        int rem = n1 & ((1 << (2 * lgo)) - 1);
        int oh = rem >> lgo, ow = rem & (outn - 1);
        int hh2 = (oh << lg) + ph, ww2 = (ow << lg) + pw;
        size_t off = (((size_t)(b_ * 4 + t_) * C_ + cch) * H_ + hh2) * W_ + ww2;
        uint2 pk;
        pk.x = f2bf(acc[j][0]) | (f2bf(acc[j][1]) << 16);
        pk.y = f2bf(acc[j][2]) | (f2bf(acc[j][3]) << 16);
        *(uint2*)&attn[off] = pk;
    }
}

// ---------------------------------------------------------------------------
// K5/K6/K7: 3x3 conv (dilation DIL, zero pad DIL) + lrelu + epilogue.
// BF: input is bf16 (else fp32). MODE 0: outf = res + lrelu(acc)
// MODE 1: outb = bf16(lrelu(acc)); MODE 2: outf += lrelu(acc).
// grid (128 rows, 16 imgs, 4 co-chunks), block 256. 32-co x 128-px tile.
// ---------------------------------------------------------------------------
template<int BF, int DIL, int MODE>
__global__ __launch_bounds__(256) void conv3_kernel(
    const void* __restrict__ inv, const float* __restrict__ Wt,
    const float* __restrict__ bias, const float* __restrict__ res,
    float* __restrict__ outf, ushort_t* __restrict__ outb)
{
    __shared__ float xt[3 * 32 * 132];   // [row][ci][2 + w + 2], 50.7 KB
    __shared__ float wtl[32 * 36];       // [ci][co pad 36], 4.6 KB
    const int h = blockIdx.x, img = blockIdx.y, cc = blockIdx.z;
    const int tid = threadIdx.x;
    const int pxq = tid & 31, coq = tid >> 5;
    const int col0 = 4 * coq;
    float acc[4][4];
    #pragma unroll
    for (int a = 0; a < 4; ++a) {
        float bb = bias[cc * 32 + col0 + a];
        #pragma unroll
        for (int e = 0; e < 4; ++e) acc[a][e] = bb;
    }
    for (int i = tid; i < 3 * 32 * 132; i += 256) xt[i] = 0.f;  // pads stay 0

    for (int cib = 0; cib < 128; cib += 32) {
        __syncthreads();
        for (int i = tid; i < 12288; i += 256) {
            int r = i >> 12, rem = i & 4095, ci = rem >> 7, wc = rem & 127;
            int sh = h + (r - 1) * DIL;
            float v = 0.f;
            if (sh >= 0 && sh < 128) {
                size_t idx = (((size_t)img * C_ + cib + ci) * H_ + sh) * W_ + wc;
                v = BF ? bf2f(((const ushort_t*)inv)[idx]) : ((const float*)inv)[idx];
            }
            xt[(r * 32 + ci) * 132 + 2 + wc] = v;
        }
        for (int tap = 0; tap < 9; ++tap) {
            __syncthreads();
            for (int i = tid; i < 1024; i += 256) {
                int ci = i >> 5, col = i & 31;
                wtl[ci * 36 + col] = Wt[((size_t)(cc * 32 + col) * C_ + cib + ci) * 9 + tap];
            }
            __syncthreads();
            const int r = tap / 3;
            const int dwd = (tap % 3 - 1) * DIL;
            const int xbase = r * 32 * 132 + 2 + pxq + dwd;
            #pragma unroll 4
            for (int ci = 0; ci < 32; ++ci) {
                float4 wv = *(const float4*)&wtl[ci * 36 + col0];
                float x0v = xt[xbase + ci * 132 + 0];
                float x1v = xt[xbase + ci * 132 + 32];
                float x2v = xt[xbase + ci * 132 + 64];
                float x3v = xt[xbase + ci * 132 + 96];
                acc[0][0] += wv.x * x0v; acc[0][1] += wv.x * x1v; acc[0][2] += wv.x * x2v; acc[0][3] += wv.x * x3v;
                acc[1][0] += wv.y * x0v; acc[1][1] += wv.y * x1v; acc[1][2] += wv.y * x2v; acc[1][3] += wv.y * x3v;
                acc[2][0] += wv.z * x0v; acc[2][1] += wv.z * x1v; acc[2][2] += wv.z * x2v; acc[2][3] += wv.z * x3v;
                acc[3][0] += wv.w * x0v; acc[3][1] += wv.w * x1v; acc[3][2] += wv.w * x2v; acc[3][3] += wv.w * x3v;
            }
        }
    }
    #pragma unroll
    for (int a = 0; a < 4; ++a) {
        int co = cc * 32 + col0 + a;
        size_t rowbase = (((size_t)img * C_ + co) * H_ + h) * W_;
        #pragma unroll
        for (int e = 0; e < 4; ++e) {
            int px = pxq + 32 * e;
            float v = acc[a][e];
            v = (v >= 0.f) ? v : 0.2f * v;
            size_t idx = rowbase + px;
            if (MODE == 0) outf[idx] = res[idx] + v;
            else if (MODE == 1) outb[idx] = (ushort_t)f2bf(v);
            else outf[idx] = outf[idx] + v;
        }
    }
}

// ---------------------------------------------------------------------------
extern "C" void kernel_launch(void* const* d_in, const int* in_sizes, int n_in,
                              void* d_out, int out_size, void* d_ws, size_t ws_size,
                              hipStream_t stream)
{
    const float* x   = (const float*)d_in[0];
    const float* Wq  = (const float*)d_in[1];
    const float* bq  = (const float*)d_in[2];
    const float* Wk  = (const float*)d_in[3];
    const float* bk  = (const float*)d_in[4];
    const float* Wv  = (const float*)d_in[5];
    const float* bv  = (const float*)d_in[6];
    const float* Wo  = (const float*)d_in[7];
    const float* bo  = (const float*)d_in[8];
    const float* Wf1 = (const float*)d_in[9];
    const float* bf1 = (const float*)d_in[10];
    const float* Wf2 = (const float*)d_in[11];
    const float* bf2 = (const float*)d_in[12];
    float* out = (float*)d_out;
    char* ws = (char*)d_ws;
    const size_t MB64 = 67108864ull;
    ushort_t* qw   = (ushort_t*)(ws);
    ushort_t* kw   = (ushort_t*)(ws + 1 * MB64);
    ushort_t* vw   = (ushort_t*)(ws + 2 * MB64);
    ushort_t* attn = (ushort_t*)(ws + 3 * MB64);
    ushort_t* ff1  = (ushort_t*)(ws + 4 * MB64);
    float*    sc   = (float*)(ws + 5 * MB64);   // <= 16 MB

    // 1) q/k/v 1x1 convs -> windowed bf16
    qkv_kernel<<<dim3(128, 16), 256, 0, stream>>>(x, Wq, bq, Wk, bk, Wv, bv, qw, kw, vw);

    // 2) per-scale attention
    static const int KS[4] = {64, 64, 4, 1};  // K-split per scale (small-n scales)
    for (int s = 0; s < 4; ++s) {
        int lg = 6 - s, outn = 128 >> lg, n = 4 * outn * outn, Dd = 32 << (2 * lg);
        int nb = (n + 63) / 64;
        if (KS[s] > 1)
            hipMemsetAsync(sc, 0, (size_t)4 * n * n * sizeof(float), stream);
        scores_kernel<<<dim3(nb, nb, 4 * KS[s]), 256, 0, stream>>>(qw, kw, sc, lg, KS[s]);
        softmax_kernel<<<dim3(4 * n), 256, 0, stream>>>(sc, n);
        pv_kernel<<<dim3(Dd / 128, (n + 31) / 32, 4), 256, 0, stream>>>(sc, vw, attn, lg);
    }

    // 3) x1 = x + lrelu(conv3x3(attn, Wo))      -> d_out (fp32)
    conv3_kernel<1, 1, 0><<<dim3(128, 16, 4), 256, 0, stream>>>(attn, Wo, bo, x, out, nullptr);
    // 4) ff1 = lrelu(conv3x3 dil2 pad2(x1, Wf1)) -> ws (bf16)
    conv3_kernel<0, 2, 1><<<dim3(128, 16, 4), 256, 0, stream>>>(out, Wf1, bf1, nullptr, nullptr, ff1);
    // 5) out = x1 + lrelu(conv3x3(ff1, Wf2))     -> d_out (fp32, RMW)
    conv3_kernel<1, 1, 2><<<dim3(128, 16, 4), 256, 0, stream>>>(ff1, Wf2, bf2, nullptr, out, nullptr);
}

// Round 2
// 1970.461 us; speedup vs baseline: 4.5527x; 4.5527x over previous
//
#include <hip/hip_runtime.h>
#include <stdint.h>

#define C_   128
#define H_   128
#define W_   128
#define HW_  (128*128)

typedef unsigned short ushort_t;
typedef __attribute__((ext_vector_type(8)))  short bf16x8;
typedef __attribute__((ext_vector_type(16))) float f32x16;

__device__ __forceinline__ float bf2f(uint32_t u) {
    union { float f; uint32_t i; } v; v.i = u << 16; return v.f;
}
__device__ __forceinline__ uint32_t f2bf(float f) {
    union { float f; uint32_t i; } v; v.f = f;
    uint32_t u = v.i;
    uint32_t r = u + 0x7FFFu + ((u >> 16) & 1u);
    return r >> 16;  // RTNE bf16 bits in low 16
}
__device__ __forceinline__ void unp8(uint4 raw, float* d) {
    d[0] = bf2f(raw.x & 0xffffu); d[1] = bf2f(raw.x >> 16);
    d[2] = bf2f(raw.y & 0xffffu); d[3] = bf2f(raw.y >> 16);
    d[4] = bf2f(raw.z & 0xffffu); d[5] = bf2f(raw.z >> 16);
    d[6] = bf2f(raw.w & 0xffffu); d[7] = bf2f(raw.w >> 16);
}
__device__ __forceinline__ void async16(const ushort_t* g, void* l) {
    __builtin_amdgcn_global_load_lds(
        (const __attribute__((address_space(1))) unsigned int*)g,
        (__attribute__((address_space(3))) unsigned int*)l, 16, 0, 0);
}

// ---------------------------------------------------------------------------
// K1: q/k/v 1x1 convs, scatter directly into per-scale windowed layout (bf16).
// ---------------------------------------------------------------------------
__global__ __launch_bounds__(256) void qkv_kernel(
    const float* __restrict__ x,
    const float* __restrict__ Wq, const float* __restrict__ bq,
    const float* __restrict__ Wk, const float* __restrict__ bk,
    const float* __restrict__ Wv, const float* __restrict__ bv,
    ushort_t* __restrict__ qw, ushort_t* __restrict__ kw, ushort_t* __restrict__ vw)
{
    __shared__ ushort_t xtb[128 * 128];   // [ci][px] bf16, 32 KB
    __shared__ float    wt[128 * 32];     // [ci][co_l] fp32, 16 KB
    const int h = blockIdx.x, img = blockIdx.y, tid = threadIdx.x;
    const float* xb = x + (size_t)img * C_ * HW_ + (size_t)h * W_;
    for (int i = tid; i < 4096; i += 256) {
        int ci = i >> 5, p4 = (i & 31) * 4;
        float4 xv = *(const float4*)&xb[(size_t)ci * HW_ + p4];
        uint2 pk;
        pk.x = f2bf(xv.x) | (f2bf(xv.y) << 16);
        pk.y = f2bf(xv.z) | (f2bf(xv.w) << 16);
        *(uint2*)&xtb[ci * 128 + p4] = pk;
    }
    const int b_ = img >> 2, t_ = img & 3;
    const int pxq = tid & 31, coq = tid >> 5;
    const int px0 = pxq * 4, col0 = coq * 4;

    for (int w3 = 0; w3 < 3; ++w3) {
        const float* Wp = (w3 == 0) ? Wq : ((w3 == 1) ? Wk : Wv);
        const float* bp = (w3 == 0) ? bq : ((w3 == 1) ? bk : bv);
        ushort_t*  outp = (w3 == 0) ? qw : ((w3 == 1) ? kw : vw);
        for (int cc = 0; cc < 4; ++cc) {
            __syncthreads();
            for (int i = tid; i < 4096; i += 256) {
                int col = i & 31, ci = i >> 5;
                wt[ci * 32 + col] = Wp[(cc * 32 + col) * 128 + ci];
            }
            __syncthreads();
            float acc[4][4];
            #pragma unroll
            for (int a = 0; a < 4; ++a) {
                float bb = bp[cc * 32 + col0 + a];
                #pragma unroll
                for (int e = 0; e < 4; ++e) acc[a][e] = bb;
            }
            #pragma unroll 4
            for (int ci = 0; ci < 128; ++ci) {
                uint2 xr = *(const uint2*)&xtb[ci * 128 + px0];
                float xv0 = bf2f(xr.x & 0xffffu), xv1 = bf2f(xr.x >> 16);
                float xv2 = bf2f(xr.y & 0xffffu), xv3 = bf2f(xr.y >> 16);
                float4 wv = *(const float4*)&wt[ci * 32 + col0];
                acc[0][0] += wv.x * xv0; acc[0][1] += wv.x * xv1; acc[0][2] += wv.x * xv2; acc[0][3] += wv.x * xv3;
                acc[1][0] += wv.y * xv0; acc[1][1] += wv.y * xv1; acc[1][2] += wv.y * xv2; acc[1][3] += wv.y * xv3;
                acc[2][0] += wv.z * xv0; acc[2][1] += wv.z * xv1; acc[2][2] += wv.z * xv2; acc[2][3] += wv.z * xv3;
                acc[3][0] += wv.w * xv0; acc[3][1] += wv.w * xv1; acc[3][2] += wv.w * xv2; acc[3][3] += wv.w * xv3;
            }
            const int lg  = 6 - cc;
            const int psz = 1 << lg, outn = 128 >> lg;
            const int Dd  = 32 << (2 * lg);
            const size_t base = (size_t)cc * 8388608u;
            const int oh = h >> lg, ph = h & (psz - 1);
            const int ow = px0 >> lg, pw0 = px0 & (psz - 1);
            const int ntok = t_ * outn * outn + oh * outn + ow;
            const size_t rowoff = base + ((size_t)(b_ * 4 * outn * outn + ntok)) * (size_t)Dd;
            #pragma unroll
            for (int a = 0; a < 4; ++a) {
                int c_local = col0 + a;
                int dd = (((c_local << lg) + ph) << lg) + pw0;
                uint2 pk;
                pk.x = f2bf(acc[a][0]) | (f2bf(acc[a][1]) << 16);
                pk.y = f2bf(acc[a][2]) | (f2bf(acc[a][3]) << 16);
                *(uint2*)&outp[rowoff + dd] = pk;
            }
        }
    }
}

// ---------------------------------------------------------------------------
// K2: scores = Q K^T / sqrt(D).
// ---------------------------------------------------------------------------
__global__ __launch_bounds__(256) void scores_kernel(
    const ushort_t* __restrict__ qw, const ushort_t* __restrict__ kw,
    float* __restrict__ sc, int lg, int ks_count)
{
    const int outn = 128 >> lg;
    const int n  = 4 * outn * outn;
    const int Dd = 32 << (2 * lg);
    const int scale = 6 - lg;
    const size_t base = (size_t)scale * 8388608u;
    const int b_ = blockIdx.z / ks_count;
    const int ks = blockIdx.z % ks_count;
    const int DdK = Dd / ks_count;
    const int n1b = blockIdx.x * 64, n2b = blockIdx.y * 64;
    const ushort_t* qb = qw + base + (size_t)b_ * (size_t)n * Dd;
    const ushort_t* kb = kw + base + (size_t)b_ * (size_t)n * Dd;
    __shared__ float qt[64 * 33];
    __shared__ float kt[64 * 33];
    const int tid = threadIdx.x;
    const int r0 = 4 * (tid >> 4), c0 = 4 * (tid & 15);
    float acc[4][4] = {};
    const int rld = tid >> 2, kb8 = (tid & 3) * 8;

    for (int k0 = ks * DdK; k0 < ks * DdK + DdK; k0 += 32) {
        __syncthreads();
        {
            float tmp[8];
            int n1 = n1b + rld;
            if (n1 < n) { uint4 raw = *(const uint4*)&qb[(size_t)n1 * Dd + k0 + kb8]; unp8(raw, tmp); }
            else { for (int j = 0; j < 8; ++j) tmp[j] = 0.f; }
            for (int j = 0; j < 8; ++j) qt[rld * 33 + kb8 + j] = tmp[j];
            int n2 = n2b + rld;
            if (n2 < n) { uint4 raw = *(const uint4*)&kb[(size_t)n2 * Dd + k0 + kb8]; unp8(raw, tmp); }
            else { for (int j = 0; j < 8; ++j) tmp[j] = 0.f; }
            for (int j = 0; j < 8; ++j) kt[rld * 33 + kb8 + j] = tmp[j];
        }
        __syncthreads();
        #pragma unroll 4
        for (int kk = 0; kk < 32; ++kk) {
            float qv[4], kv[4];
            #pragma unroll
            for (int a = 0; a < 4; ++a) { qv[a] = qt[(r0 + a) * 33 + kk]; kv[a] = kt[(c0 + a) * 33 + kk]; }
            #pragma unroll
            for (int a = 0; a < 4; ++a)
                #pragma unroll
                for (int e = 0; e < 4; ++e) acc[a][e] += qv[a] * kv[e];
        }
    }
    const float scl = rsqrtf((float)Dd);
    #pragma unroll
    for (int a = 0; a < 4; ++a) {
        int n1 = n1b + r0 + a;
        int n2 = n2b + c0;
        if (n1 < n && n2 < n) {
            size_t off = ((size_t)b_ * n + n1) * (size_t)n + n2;
            if (ks_count == 1) {
                float4 o = make_float4(acc[a][0] * scl, acc[a][1] * scl, acc[a][2] * scl, acc[a][3] * scl);
                *(float4*)&sc[off] = o;
            } else {
                #pragma unroll
                for (int e = 0; e < 4; ++e) atomicAdd(&sc[off + e], acc[a][e] * scl);
            }
        }
    }
}

// ---------------------------------------------------------------------------
// K3: row softmax in place.
// ---------------------------------------------------------------------------
__global__ __launch_bounds__(256) void softmax_kernel(float* __restrict__ sc, int n)
{
    const int row = blockIdx.x;
    float* p = sc + (size_t)row * n;
    const int tid = threadIdx.x;
    float v[4];
    #pragma unroll
    for (int j = 0; j < 4; ++j) { int idx = tid + 256 * j; v[j] = (idx < n) ? p[idx] : -3.0e38f; }
    float m = fmaxf(fmaxf(v[0], v[1]), fmaxf(v[2], v[3]));
    #pragma unroll
    for (int off = 32; off >= 1; off >>= 1) m = fmaxf(m, __shfl_xor(m, off));
    __shared__ float red[4];
    const int wid = tid >> 6, lane = tid & 63;
    if (lane == 0) red[wid] = m;
    __syncthreads();
    m = fmaxf(fmaxf(red[0], red[1]), fmaxf(red[2], red[3]));
    float e[4]; float s = 0.f;
    #pragma unroll
    for (int j = 0; j < 4; ++j) { int idx = tid + 256 * j; e[j] = (idx < n) ? __expf(v[j] - m) : 0.f; s += e[j]; }
    #pragma unroll
    for (int off = 32; off >= 1; off >>= 1) s += __shfl_xor(s, off);
    __syncthreads();
    if (lane == 0) red[wid] = s;
    __syncthreads();
    s = red[0] + red[1] + red[2] + red[3];
    float inv = 1.0f / s;
    #pragma unroll
    for (int j = 0; j < 4; ++j) { int idx = tid + 256 * j; if (idx < n) p[idx] = e[j] * inv; }
}

// ---------------------------------------------------------------------------
// K4: y = P V, scatter to attn image (NCHW bf16).
// ---------------------------------------------------------------------------
__global__ __launch_bounds__(256) void pv_kernel(
    const float* __restrict__ sc, const ushort_t* __restrict__ vw,
    ushort_t* __restrict__ attn, int lg)
{
    const int outn = 128 >> lg, psz = 1 << lg;
    const int n  = 4 * outn * outn;
    const int Dd = 32 << (2 * lg);
    const int scale = 6 - lg;
    const size_t base = (size_t)scale * 8388608u;
    const int b_ = blockIdx.z;
    const int dd0 = blockIdx.x * 128, n1b = blockIdx.y * 32;
    const ushort_t* vb = vw + base + (size_t)b_ * (size_t)n * Dd;
    const float* pb = sc + (size_t)b_ * n * n;
    __shared__ float pt[32 * 33];
    __shared__ float vt[32 * 132];
    const int tid = threadIdx.x;
    const int cq = tid & 31, rq = tid >> 5;
    const int r0 = 4 * rq, c0v = 4 * cq;
    float acc[4][4] = {};

    for (int m0 = 0; m0 < n; m0 += 32) {
        __syncthreads();
        for (int i = tid; i < 1024; i += 256) {
            int r = i >> 5, m = i & 31;
            int n1 = n1b + r, mm = m0 + m;
            pt[r * 33 + m] = (n1 < n && mm < n) ? pb[(size_t)n1 * n + mm] : 0.f;
        }
        for (int i = tid; i < 512; i += 256) {
            int m = i >> 4, c8 = (i & 15) * 8;
            int mm = m0 + m;
            float tmp[8];
            if (mm < n) { uint4 raw = *(const uint4*)&vb[(size_t)mm * Dd + dd0 + c8]; unp8(raw, tmp); }
            else { for (int j = 0; j < 8; ++j) tmp[j] = 0.f; }
            for (int j = 0; j < 8; ++j) vt[m * 132 + c8 + j] = tmp[j];
        }
        __syncthreads();
        #pragma unroll 4
        for (int m = 0; m < 32; ++m) {
            float pv4[4];
            #pragma unroll
            for (int j = 0; j < 4; ++j) pv4[j] = pt[(r0 + j) * 33 + m];
            float4 vv = *(const float4*)&vt[m * 132 + c0v];
            #pragma unroll
            for (int j = 0; j < 4; ++j) {
                acc[j][0] += pv4[j] * vv.x; acc[j][1] += pv4[j] * vv.y;
                acc[j][2] += pv4[j] * vv.z; acc[j][3] += pv4[j] * vv.w;
            }
        }
    }
    const int lgo = 7 - lg;
    const int dd = dd0 + c0v;
    const int c_local = dd >> (2 * lg);
    const int p2 = dd & (psz * psz - 1);
    const int ph = p2 >> lg, pw = p2 & (psz - 1);
    const int cch = scale * 32 + c_local;
    #pragma unroll
    for (int j = 0; j < 4; ++j) {
        int n1 = n1b + r0 + j;
        if (n1 >= n) continue;
        int t_ = n1 >> (2 * lgo);
        int rem = n1 & ((1 << (2 * lgo)) - 1);
        int oh = rem >> lgo, ow = rem & (outn - 1);
        int hh2 = (oh << lg) + ph, ww2 = (ow << lg) + pw;
        size_t off = (((size_t)(b_ * 4 + t_) * C_ + cch) * H_ + hh2) * W_ + ww2;
        uint2 pk;
        pk.x = f2bf(acc[j][0]) | (f2bf(acc[j][1]) << 16);
        pk.y = f2bf(acc[j][2]) | (f2bf(acc[j][3]) << 16);
        *(uint2*)&attn[off] = pk;
    }
}

// ---------------------------------------------------------------------------
// K5: weight prepack into MFMA A-fragment-linear order (bf16).
// Frag f = ((cc*9 + tap)*2 + s)*4 + cot; elem = f*512 + lane*8 + j holds
// W[co = cot*32+(lane&31)][ci = cc*32+s*16+(lane>>5)*8+j][tap].
// ---------------------------------------------------------------------------
__global__ __launch_bounds__(256) void prepack_kernel(
    const float* __restrict__ Wo, const float* __restrict__ Wf1,
    const float* __restrict__ Wf2, ushort_t* __restrict__ Wp)
{
    int t = blockIdx.x * 256 + threadIdx.x;          // 0..147455
    const float* W = (blockIdx.y == 0) ? Wo : ((blockIdx.y == 1) ? Wf1 : Wf2);
    ushort_t* dst = Wp + (size_t)blockIdx.y * 147456;
    int j = t & 7, lane = (t >> 3) & 63, f = t >> 9;
    int cot = f & 3, s = (f >> 2) & 1, tap = (f >> 3) % 9, cc = f / 72;
    int co = cot * 32 + (lane & 31);
    int ci = cc * 32 + s * 16 + (lane >> 5) * 8 + j;
    dst[t] = (ushort_t)f2bf(W[((size_t)co * 128 + ci) * 9 + tap]);
}

// ---------------------------------------------------------------------------
// K6: NCHW (fp32 or bf16) -> NHWC bf16 transpose. Tile: 128 c x 128 hw.
// LDS [hw][granule-swizzled c], granule(8 elem) g' = g ^ ((hw>>3)&7).
// grid (128, 16), block 256.
// ---------------------------------------------------------------------------
template<int SRC_F32>
__global__ __launch_bounds__(256) void nchw2nhwc_kernel(
    const void* __restrict__ in, ushort_t* __restrict__ out)
{
    __shared__ ushort_t tile[128 * 136];   // 34.8 KB
    const int img = blockIdx.y, hwb = blockIdx.x * 128;
    const int tid = threadIdx.x;
    #pragma unroll
    for (int i = 0; i < 8; ++i) {
        int idx = tid + 256 * i;            // 0..2047
        int c = idx >> 4, hw8 = (idx & 15) * 8;
        size_t src = ((size_t)img * 128 + c) * (size_t)HW_ + hwb + hw8;
        ushort_t v[8];
        if (SRC_F32) {
            const float4* fp = (const float4*)&((const float*)in)[src];
            float4 f0 = fp[0], f1 = fp[1];
            v[0] = (ushort_t)f2bf(f0.x); v[1] = (ushort_t)f2bf(f0.y);
            v[2] = (ushort_t)f2bf(f0.z); v[3] = (ushort_t)f2bf(f0.w);
            v[4] = (ushort_t)f2bf(f1.x); v[5] = (ushort_t)f2bf(f1.y);
            v[6] = (ushort_t)f2bf(f1.z); v[7] = (ushort_t)f2bf(f1.w);
        } else {
            uint4 raw = *(const uint4*)&((const ushort_t*)in)[src];
            v[0] = raw.x & 0xffffu; v[1] = raw.x >> 16;
            v[2] = raw.y & 0xffffu; v[3] = raw.y >> 16;
            v[4] = raw.z & 0xffffu; v[5] = raw.z >> 16;
            v[6] = raw.w & 0xffffu; v[7] = raw.w >> 16;
        }
        #pragma unroll
        for (int k = 0; k < 8; ++k) {
            int hw = hw8 + k;
            int g  = (c >> 3) ^ ((hw >> 3) & 7);
            tile[hw * 136 + g * 8 + (c & 7)] = v[k];
        }
    }
    __syncthreads();
    #pragma unroll
    for (int i = 0; i < 8; ++i) {
        int idx = tid + 256 * i;
        int hw = idx >> 4, g = idx & 15;
        int gs = g ^ ((hw >> 3) & 7);
        uint4 raw = *(const uint4*)&tile[hw * 136 + gs * 8];
        *(uint4*)&out[((size_t)img * HW_ + hwb + hw) * 128 + g * 8] = raw;
    }
}

// ---------------------------------------------------------------------------
// K7: MFMA implicit-GEMM 3x3 conv (dil DIL, pad DIL) + bias + lrelu + epilogue.
// In: NHWC bf16. Out tile per block: 2 rows x 128 px x 128 co.
// Waves: (row r = wv&1) x (co half = (wv>>1)*64). Wave tile 128px x 64co.
// A = prepacked weights (global, frag-linear); B = input (LDS, swizzled).
// MODE 0: outf = res + lrelu(acc+bias);  MODE 1: outb = bf16(lrelu(acc+bias));
// MODE 2: outf += lrelu(acc+bias).
// grid (64, 16), block 256.
// ---------------------------------------------------------------------------
template<int DIL, int MODE>
__global__ __launch_bounds__(256, 2) void conv3m_kernel(
    const ushort_t* __restrict__ in, const ushort_t* __restrict__ Wp,
    const float* __restrict__ bias, const float* __restrict__ res,
    float* __restrict__ outf, ushort_t* __restrict__ outb,
    const ushort_t* __restrict__ zp)
{
    constexpr int NSLOT = (DIL == 1) ? 4 : 6;
    __shared__ ushort_t lds[NSLOT * 144 * 32];   // NSLOT*9216 bytes
    const int h0 = blockIdx.x * 2, img = blockIdx.y;
    const int tid = threadIdx.x, lane = tid & 63, wv = tid >> 6;
    const int r = wv & 1;             // output row within pair
    const int wco = (wv >> 1) * 64;   // co half
    const int imrow_out = h0 + r;

    f32x16 acc[4][2];
    #pragma unroll
    for (int tm = 0; tm < 4; ++tm)
        #pragma unroll
        for (int tn = 0; tn < 2; ++tn)
            #pragma unroll
            for (int k = 0; k < 16; ++k) acc[tm][tn][k] = 0.f;

    for (int cc = 0; cc < 4; ++cc) {
        const int cib = cc * 32;
        __syncthreads();   // previous chunk's reads complete before overwrite
        // ---- stage input chunk: NSLOT rows x 144 px x 32 ci, zero-pad via zp
        for (int kb = wv; kb < NSLOT * 9; kb += 4) {
            int slot = kb / 9, px0 = (kb % 9) * 16;
            int px = px0 + (lane >> 2), chunk = lane & 3;
            int wc = px - DIL, ir = h0 - DIL + slot;
            const ushort_t* src;
            if (wc >= 0 && wc < 128 && ir >= 0 && ir < 128)
                src = in + (((size_t)(img * 128 + ir) * 128 + wc) * 128 + cib
                            + ((chunk ^ ((px >> 1) & 3)) << 3));
            else
                src = zp + lane * 8;
            async16(src, (char*)lds + kb * 1024);
        }
        asm volatile("s_waitcnt vmcnt(0)" ::: "memory");
        __syncthreads();
        // ---- compute 9 taps x 2 k16-steps
        for (int tap = 0; tap < 9; ++tap) {
            const int tr = tap / 3, tc = tap % 3;
            const int slot = r + tr * DIL;
            const ushort_t* sb = lds + slot * 4608;   // 4608 ushorts = 9216 B
            #pragma unroll
            for (int s = 0; s < 2; ++s) {
                const int fbase = ((cc * 9 + tap) * 2 + s) * 4 + (wco >> 5);
                bf16x8 a0 = *(const bf16x8*)(Wp + ((size_t)fbase * 64 + lane) * 8);
                bf16x8 a1 = *(const bf16x8*)(Wp + ((size_t)(fbase + 1) * 64 + lane) * 8);
                const int kch = s * 2 + (lane >> 5);
                bf16x8 b[4];
                #pragma unroll
                for (int tm = 0; tm < 4; ++tm) {
                    int px = tm * 32 + (lane & 31) + tc * DIL;
                    b[tm] = *(const bf16x8*)(sb + px * 32 + ((kch ^ ((px >> 1) & 3)) << 3));
                }
                #pragma unroll
                for (int tm = 0; tm < 4; ++tm) {
                    acc[tm][0] = __builtin_amdgcn_mfma_f32_32x32x16_bf16(a0, b[tm], acc[tm][0], 0, 0, 0);
                    acc[tm][1] = __builtin_amdgcn_mfma_f32_32x32x16_bf16(a1, b[tm], acc[tm][1], 0, 0, 0);
                }
            }
        }
    }
    // ---- epilogue: bias + lrelu (+ residual / RMW / bf16 store)
    #pragma unroll
    for (int tn = 0; tn < 2; ++tn) {
        #pragma unroll
        for (int rg = 0; rg < 16; ++rg) {
            int co = wco + tn * 32 + (rg & 3) + 8 * (rg >> 2) + 4 * (lane >> 5);
            float bb = bias[co];
            size_t rowbase = (((size_t)(img * 128 + co)) * 128 + imrow_out) * 128;
            #pragma unroll
            for (int tm = 0; tm < 4; ++tm) {
                int wcol = tm * 32 + (lane & 31);
                float v = acc[tm][tn][rg] + bb;
                v = (v >= 0.f) ? v : 0.2f * v;
                size_t idx = rowbase + wcol;
                if (MODE == 0)      outf[idx] = res[idx] + v;
                else if (MODE == 1) outb[idx] = (ushort_t)f2bf(v);
                else                outf[idx] = outf[idx] + v;
            }
        }
    }
}

// ---------------------------------------------------------------------------
extern "C" void kernel_launch(void* const* d_in, const int* in_sizes, int n_in,
                              void* d_out, int out_size, void* d_ws, size_t ws_size,
                              hipStream_t stream)
{
    const float* x   = (const float*)d_in[0];
    const float* Wq  = (const float*)d_in[1];
    const float* bq  = (const float*)d_in[2];
    const float* Wk  = (const float*)d_in[3];
    const float* bk  = (const float*)d_in[4];
    const float* Wv  = (const float*)d_in[5];
    const float* bv  = (const float*)d_in[6];
    const float* Wo  = (const float*)d_in[7];
    const float* bo  = (const float*)d_in[8];
    const float* Wf1 = (const float*)d_in[9];
    const float* bf1 = (const float*)d_in[10];
    const float* Wf2 = (const float*)d_in[11];
    const float* bf2 = (const float*)d_in[12];
    float* out = (float*)d_out;
    char* ws = (char*)d_ws;
    const size_t MB64 = 67108864ull;
    ushort_t* qw   = (ushort_t*)(ws);                 // also reused as NHWC buf
    ushort_t* kw   = (ushort_t*)(ws + 1 * MB64);
    ushort_t* vw   = (ushort_t*)(ws + 2 * MB64);
    ushort_t* attn = (ushort_t*)(ws + 3 * MB64);      // also reused as ff1 buf
    float*    sc   = (float*)(ws + 5 * MB64);         // <= 16.8 MB
    ushort_t* Wp   = (ushort_t*)(ws + 5 * MB64 + 17 * 1048576);  // 0.85 MB
    ushort_t* zp   = (ushort_t*)(ws + 5 * MB64 + 18 * 1048576);  // 1 KB zeros
    ushort_t* nhwc = qw;
    ushort_t* ff1  = attn;

    hipMemsetAsync(zp, 0, 1024, stream);
    prepack_kernel<<<dim3(576, 3), 256, 0, stream>>>(Wo, Wf1, Wf2, Wp);

    // 1) q/k/v 1x1 convs -> windowed bf16
    qkv_kernel<<<dim3(128, 16), 256, 0, stream>>>(x, Wq, bq, Wk, bk, Wv, bv, qw, kw, vw);

    // 2) per-scale attention
    static const int KS[4] = {64, 64, 4, 1};
    for (int s = 0; s < 4; ++s) {
        int lg = 6 - s, outn = 128 >> lg, n = 4 * outn * outn, Dd = 32 << (2 * lg);
        int nb = (n + 63) / 64;
        if (KS[s] > 1)
            hipMemsetAsync(sc, 0, (size_t)4 * n * n * sizeof(float), stream);
        scores_kernel<<<dim3(nb, nb, 4 * KS[s]), 256, 0, stream>>>(qw, kw, sc, lg, KS[s]);
        softmax_kernel<<<dim3(4 * n), 256, 0, stream>>>(sc, n);
        pv_kernel<<<dim3(Dd / 128, (n + 31) / 32, 4), 256, 0, stream>>>(sc, vw, attn, lg);
    }

    // 3) attn NCHW-bf16 -> NHWC-bf16 (qw region is free now)
    nchw2nhwc_kernel<0><<<dim3(128, 16), 256, 0, stream>>>(attn, nhwc);
    // 4) x1 = x + lrelu(conv3x3(attn)) -> d_out fp32 NCHW
    conv3m_kernel<1, 0><<<dim3(64, 16), 256, 0, stream>>>(nhwc, Wp, bo, x, out, nullptr, zp);
    // 5) x1 -> NHWC bf16
    nchw2nhwc_kernel<1><<<dim3(128, 16), 256, 0, stream>>>(out, nhwc);
    // 6) ff1 = lrelu(conv3x3 dil2(x1)) -> bf16 NCHW (attn region is free now)
    conv3m_kernel<2, 1><<<dim3(64, 16), 256, 0, stream>>>(nhwc, Wp + 147456, bf1, nullptr, nullptr, ff1, zp);
    // 7) ff1 -> NHWC bf16
    nchw2nhwc_kernel<0><<<dim3(128, 16), 256, 0, stream>>>(ff1, nhwc);
    // 8) out = x1 + lrelu(conv3x3(ff1)) -> d_out fp32 NCHW (RMW)
    conv3m_kernel<1, 2><<<dim3(64, 16), 256, 0, stream>>>(nhwc, Wp + 2 * 147456, bf2, nullptr, out, nullptr, zp);
}

// Round 3
// 936.958 us; speedup vs baseline: 9.5746x; 2.1030x over previous
//
#include <hip/hip_runtime.h>
#include <stdint.h>

#define C_   128
#define H_   128
#define W_   128
#define HW_  (128*128)

typedef unsigned short ushort_t;
typedef __attribute__((ext_vector_type(8)))  short bf16x8;
typedef __attribute__((ext_vector_type(16))) float f32x16;

__device__ __forceinline__ float bf2f(uint32_t u) {
    union { float f; uint32_t i; } v; v.i = u << 16; return v.f;
}
__device__ __forceinline__ uint32_t f2bf(float f) {
    union { float f; uint32_t i; } v; v.f = f;
    uint32_t u = v.i;
    uint32_t r = u + 0x7FFFu + ((u >> 16) & 1u);
    return r >> 16;  // RTNE bf16 bits in low 16
}
__device__ __forceinline__ void async16(const ushort_t* g, void* l) {
    __builtin_amdgcn_global_load_lds(
        (const __attribute__((address_space(1))) unsigned int*)g,
        (__attribute__((address_space(3))) unsigned int*)l, 16, 0, 0);
}

// ---------------------------------------------------------------------------
// K-prepack A: conv weights -> MFMA A-fragment-linear order (bf16).
// ---------------------------------------------------------------------------
__global__ __launch_bounds__(256) void prepack_kernel(
    const float* __restrict__ Wo, const float* __restrict__ Wf1,
    const float* __restrict__ Wf2, ushort_t* __restrict__ Wp)
{
    int t = blockIdx.x * 256 + threadIdx.x;          // 0..147455
    const float* W = (blockIdx.y == 0) ? Wo : ((blockIdx.y == 1) ? Wf1 : Wf2);
    ushort_t* dst = Wp + (size_t)blockIdx.y * 147456;
    int j = t & 7, lane = (t >> 3) & 63, f = t >> 9;
    int cot = f & 3, s = (f >> 2) & 1, tap = (f >> 3) % 9, cc = f / 72;
    int co = cot * 32 + (lane & 31);
    int ci = cc * 32 + s * 16 + (lane >> 5) * 8 + j;
    dst[t] = (ushort_t)f2bf(W[((size_t)co * 128 + ci) * 9 + tap]);
}

// ---------------------------------------------------------------------------
// K-prepack B: 1x1 qkv weights -> A-fragment-linear (bf16). f = s*4+cot.
// grid (64, 3).
// ---------------------------------------------------------------------------
__global__ __launch_bounds__(256) void prepack1_kernel(
    const float* __restrict__ Wq, const float* __restrict__ Wk,
    const float* __restrict__ Wv, ushort_t* __restrict__ Wqkv)
{
    int t = blockIdx.x * 256 + threadIdx.x;          // 0..16383
    const float* W = (blockIdx.y == 0) ? Wq : ((blockIdx.y == 1) ? Wk : Wv);
    ushort_t* dst = Wqkv + (size_t)blockIdx.y * 16384;
    int j = t & 7, lane = (t >> 3) & 63, f = t >> 9;  // f 0..31
    int cot = f & 3, s = f >> 2;
    int co = cot * 32 + (lane & 31);
    int ci = s * 16 + (lane >> 5) * 8 + j;
    dst[t] = (ushort_t)f2bf(W[(size_t)co * 128 + ci]);
}

// ---------------------------------------------------------------------------
// NCHW (fp32 or bf16) -> NHWC bf16 transpose. grid (128, 16).
// ---------------------------------------------------------------------------
template<int SRC_F32>
__global__ __launch_bounds__(256) void nchw2nhwc_kernel(
    const void* __restrict__ in, ushort_t* __restrict__ out)
{
    __shared__ ushort_t tile[128 * 136];
    const int img = blockIdx.y, hwb = blockIdx.x * 128;
    const int tid = threadIdx.x;
    #pragma unroll
    for (int i = 0; i < 8; ++i) {
        int idx = tid + 256 * i;
        int c = idx >> 4, hw8 = (idx & 15) * 8;
        size_t src = ((size_t)img * 128 + c) * (size_t)HW_ + hwb + hw8;
        ushort_t v[8];
        if (SRC_F32) {
            const float4* fp = (const float4*)&((const float*)in)[src];
            float4 f0 = fp[0], f1 = fp[1];
            v[0] = (ushort_t)f2bf(f0.x); v[1] = (ushort_t)f2bf(f0.y);
            v[2] = (ushort_t)f2bf(f0.z); v[3] = (ushort_t)f2bf(f0.w);
            v[4] = (ushort_t)f2bf(f1.x); v[5] = (ushort_t)f2bf(f1.y);
            v[6] = (ushort_t)f2bf(f1.z); v[7] = (ushort_t)f2bf(f1.w);
        } else {
            uint4 raw = *(const uint4*)&((const ushort_t*)in)[src];
            v[0] = raw.x & 0xffffu; v[1] = raw.x >> 16;
            v[2] = raw.y & 0xffffu; v[3] = raw.y >> 16;
            v[4] = raw.z & 0xffffu; v[5] = raw.z >> 16;
            v[6] = raw.w & 0xffffu; v[7] = raw.w >> 16;
        }
        #pragma unroll
        for (int k = 0; k < 8; ++k) {
            int hw = hw8 + k;
            int g  = (c >> 3) ^ ((hw >> 3) & 7);
            tile[hw * 136 + g * 8 + (c & 7)] = v[k];
        }
    }
    __syncthreads();
    #pragma unroll
    for (int i = 0; i < 8; ++i) {
        int idx = tid + 256 * i;
        int hw = idx >> 4, g = idx & 15;
        int gs = g ^ ((hw >> 3) & 7);
        uint4 raw = *(const uint4*)&tile[hw * 136 + gs * 8];
        *(uint4*)&out[((size_t)img * HW_ + hwb + hw) * 128 + g * 8] = raw;
    }
}

// ---------------------------------------------------------------------------
// qkv MFMA: out[co][px] = W x per image, NHWC bf16 input, windowed scatter.
// grid (64 row-pairs, 16 imgs, 3 = q/k/v), block 256 (4 waves).
// ---------------------------------------------------------------------------
__global__ __launch_bounds__(256, 2) void qkvm_kernel(
    const ushort_t* __restrict__ xn, const ushort_t* __restrict__ Wqkv,
    const float* __restrict__ bq, const float* __restrict__ bk,
    const float* __restrict__ bv,
    ushort_t* __restrict__ qw, ushort_t* __restrict__ kw,
    ushort_t* __restrict__ vw)
{
    __shared__ ushort_t lds[2 * 4096];   // 2 rows x 128 px x 32 ci, 16 KB
    const int h0 = blockIdx.x * 2, img = blockIdx.y, w3 = blockIdx.z;
    const int tid = threadIdx.x, lane = tid & 63, wv = tid >> 6;
    const int r = wv & 1, wco = (wv >> 1) * 64;
    const ushort_t* Wb = Wqkv + (size_t)w3 * 16384;
    const float* bias = (w3 == 0) ? bq : ((w3 == 1) ? bk : bv);
    ushort_t* outp = (w3 == 0) ? qw : ((w3 == 1) ? kw : vw);
    const int b_ = img >> 2, t_ = img & 3, h = h0 + r;

    f32x16 acc[4][2];
    #pragma unroll
    for (int tm = 0; tm < 4; ++tm)
        #pragma unroll
        for (int tn = 0; tn < 2; ++tn)
            #pragma unroll
            for (int k = 0; k < 16; ++k) acc[tm][tn][k] = 0.f;

    for (int cc = 0; cc < 4; ++cc) {
        __syncthreads();
        for (int kb = wv; kb < 16; kb += 4) {
            int slot = kb >> 3, px0 = (kb & 7) * 16;
            int px = px0 + (lane >> 2), chunk = lane & 3;
            const ushort_t* src = xn + (((size_t)(img * 128 + h0 + slot) * 128 + px) * 128
                                        + cc * 32 + ((chunk ^ ((px >> 1) & 3)) << 3));
            async16(src, (char*)lds + kb * 1024);
        }
        asm volatile("s_waitcnt vmcnt(0)" ::: "memory");
        __syncthreads();
        const ushort_t* sb = lds + r * 4096;
        #pragma unroll
        for (int s2 = 0; s2 < 2; ++s2) {
            const int s = cc * 2 + s2;
            const int fbase = s * 4 + (wco >> 5);
            bf16x8 a0 = *(const bf16x8*)(Wb + ((size_t)fbase * 64 + lane) * 8);
            bf16x8 a1 = *(const bf16x8*)(Wb + ((size_t)(fbase + 1) * 64 + lane) * 8);
            const int kch = s2 * 2 + (lane >> 5);
            bf16x8 b[4];
            #pragma unroll
            for (int tm = 0; tm < 4; ++tm) {
                int px = tm * 32 + (lane & 31);
                b[tm] = *(const bf16x8*)(sb + px * 32 + ((kch ^ ((px >> 1) & 3)) << 3));
            }
            #pragma unroll
            for (int tm = 0; tm < 4; ++tm) {
                acc[tm][0] = __builtin_amdgcn_mfma_f32_32x32x16_bf16(a0, b[tm], acc[tm][0], 0, 0, 0);
                acc[tm][1] = __builtin_amdgcn_mfma_f32_32x32x16_bf16(a1, b[tm], acc[tm][1], 0, 0, 0);
            }
        }
    }
    // epilogue: bias + windowed scatter (bf16 singles, runs of psz)
    #pragma unroll
    for (int tn = 0; tn < 2; ++tn) {
        const int scale = (wco >> 5) + tn;
        const int lg = 6 - scale, psz = 1 << lg, outn = 128 >> lg;
        const int Dd = 32 << (2 * lg);
        const int oh = h >> lg, ph = h & (psz - 1);
        const size_t base = (size_t)scale * 8388608u
            + ((size_t)((b_ * 4 + t_) * outn * outn + oh * outn)) * (size_t)Dd;
        #pragma unroll
        for (int rg = 0; rg < 16; ++rg) {
            int c_local = (rg & 3) + 8 * (rg >> 2) + 4 * (lane >> 5);
            float bb = bias[scale * 32 + c_local];
            size_t K1 = base + (size_t)(((c_local << lg) + ph) << lg);
            #pragma unroll
            for (int tm = 0; tm < 4; ++tm) {
                int px = tm * 32 + (lane & 31);
                int ow = px >> lg, pw = px & (psz - 1);
                outp[K1 + (size_t)ow * Dd + pw] = (ushort_t)f2bf(acc[tm][tn][rg] + bb);
            }
        }
    }
}

// ---------------------------------------------------------------------------
// V transpose per scale: vw slice [b][tok][Dd] -> vt [b][Dd][tok].
// 8x8 register-block transpose; grid (Dd/128, ceil(n/128), 4).
// ---------------------------------------------------------------------------
__global__ __launch_bounds__(256) void vtrans_kernel(
    const ushort_t* __restrict__ src, ushort_t* __restrict__ dst, int n, int Dd)
{
    const int b_ = blockIdx.z;
    const int ddb = blockIdx.x * 128, tokb = blockIdx.y * 128;
    const int tid = threadIdx.x;
    const int ti = tid & 15, tj = tid >> 4;
    const int tok0 = tokb + ti * 8, dd0 = ddb + tj * 8;
    if (tok0 >= n) return;
    const ushort_t* s = src + (size_t)b_ * (size_t)n * Dd;
    ushort_t* d = dst + (size_t)b_ * (size_t)n * Dd;
    ushort_t a[8][8];
    #pragma unroll
    for (int e = 0; e < 8; ++e)
        *(uint4*)a[e] = *(const uint4*)&s[(size_t)(tok0 + e) * Dd + dd0];
    #pragma unroll
    for (int q = 0; q < 8; ++q) {
        ushort_t o[8];
        #pragma unroll
        for (int e = 0; e < 8; ++e) o[e] = a[e][q];
        *(uint4*)&d[(size_t)(dd0 + q) * n + tok0] = *(uint4*)o;
    }
}

// ---------------------------------------------------------------------------
// scores MFMA: sc[b][n1][n2] = Q.K^T/sqrt(Dd). Frags direct from global.
// CFG0: block 128x128 (wave 64x64); CFG1: n=64 block 64x64 (wave 32x32);
// CFG2: n=16 single 32x32 tile, waves split K. KS>1 -> atomicAdd.
// ---------------------------------------------------------------------------
template<int CFG>
__global__ __launch_bounds__(256) void scoresm_kernel(
    const ushort_t* __restrict__ qw, const ushort_t* __restrict__ kw,
    float* __restrict__ sc, int lg, int ks_count)
{
    const int outn = 128 >> lg;
    const int n = 4 * outn * outn;
    const int Dd = 32 << (2 * lg);
    const int scale = 6 - lg;
    const size_t base = (size_t)scale * 8388608u;
    const int b_ = blockIdx.z / ks_count, ks = blockIdx.z % ks_count;
    const int DdK = Dd / ks_count;
    const int tid = threadIdx.x, lane = tid & 63, wv = tid >> 6;
    const ushort_t* qb = qw + base + (size_t)b_ * (size_t)n * Dd;
    const ushort_t* kb = kw + base + (size_t)b_ * (size_t)n * Dd;
    float* scb = sc + (size_t)b_ * n * n;
    const float scl = rsqrtf((float)Dd);
    const int koff = (lane >> 5) * 8;
    constexpr int MF = (CFG == 0) ? 2 : 1;
    const int mb = (CFG == 0) ? blockIdx.x * 128 + (wv & 1) * 64
                 : (CFG == 1) ? (wv & 1) * 32 : 0;
    const int nb = (CFG == 0) ? blockIdx.y * 128 + (wv >> 1) * 64
                 : (CFG == 1) ? (wv >> 1) * 32 : 0;

    f32x16 acc[MF][MF];
    #pragma unroll
    for (int i = 0; i < MF; ++i)
        #pragma unroll
        for (int j = 0; j < MF; ++j)
            #pragma unroll
            for (int k = 0; k < 16; ++k) acc[i][j][k] = 0.f;

    int mrow[MF], nrow[MF];
    #pragma unroll
    for (int i = 0; i < MF; ++i) {
        int mr = mb + i * 32 + (lane & 31);
        int nr = nb + i * 32 + (lane & 31);
        if (CFG == 2) { if (mr >= n) mr = n - 1; if (nr >= n) nr = n - 1; }
        mrow[i] = mr; nrow[i] = nr;
    }
    int k0beg = ks * DdK, k0end = k0beg + DdK;
    if (CFG == 2) { int DdW = DdK >> 2; k0beg += wv * DdW; k0end = k0beg + DdW; }

    for (int k0 = k0beg; k0 < k0end; k0 += 16) {
        bf16x8 a[MF], b[MF];
        #pragma unroll
        for (int i = 0; i < MF; ++i)
            a[i] = *(const bf16x8*)(qb + (size_t)mrow[i] * Dd + k0 + koff);
        #pragma unroll
        for (int j = 0; j < MF; ++j)
            b[j] = *(const bf16x8*)(kb + (size_t)nrow[j] * Dd + k0 + koff);
        #pragma unroll
        for (int i = 0; i < MF; ++i)
            #pragma unroll
            for (int j = 0; j < MF; ++j)
                acc[i][j] = __builtin_amdgcn_mfma_f32_32x32x16_bf16(a[i], b[j], acc[i][j], 0, 0, 0);
    }

    #pragma unroll
    for (int i = 0; i < MF; ++i)
        #pragma unroll
        for (int j = 0; j < MF; ++j)
            #pragma unroll
            for (int rg = 0; rg < 16; ++rg) {
                int row = mb + i * 32 + (rg & 3) + 8 * (rg >> 2) + 4 * (lane >> 5);
                int col = nb + j * 32 + (lane & 31);
                if (CFG == 2 && (row >= n || col >= n)) continue;
                float v = acc[i][j][rg] * scl;
                size_t off = (size_t)row * n + col;
                if (ks_count == 1) scb[off] = v;
                else atomicAdd(&scb[off], v);
            }
}

// ---------------------------------------------------------------------------
// softmax rows of sc (fp32) -> pbf (bf16). grid = 4*n, block 256, n<=1024.
// ---------------------------------------------------------------------------
__global__ __launch_bounds__(256) void softmax_kernel(
    const float* __restrict__ sc, ushort_t* __restrict__ pbf, int n)
{
    const int row = blockIdx.x;
    const float* p = sc + (size_t)row * n;
    const int tid = threadIdx.x;
    float v[4];
    #pragma unroll
    for (int j = 0; j < 4; ++j) { int idx = tid + 256 * j; v[j] = (idx < n) ? p[idx] : -3.0e38f; }
    float m = fmaxf(fmaxf(v[0], v[1]), fmaxf(v[2], v[3]));
    #pragma unroll
    for (int off = 32; off >= 1; off >>= 1) m = fmaxf(m, __shfl_xor(m, off));
    __shared__ float red[4];
    const int wid = tid >> 6, lane = tid & 63;
    if (lane == 0) red[wid] = m;
    __syncthreads();
    m = fmaxf(fmaxf(red[0], red[1]), fmaxf(red[2], red[3]));
    float e[4]; float s = 0.f;
    #pragma unroll
    for (int j = 0; j < 4; ++j) { int idx = tid + 256 * j; e[j] = (idx < n) ? __expf(v[j] - m) : 0.f; s += e[j]; }
    #pragma unroll
    for (int off = 32; off >= 1; off >>= 1) s += __shfl_xor(s, off);
    __syncthreads();
    if (lane == 0) red[wid] = s;
    __syncthreads();
    s = red[0] + red[1] + red[2] + red[3];
    float inv = 1.0f / s;
    #pragma unroll
    for (int j = 0; j < 4; ++j) {
        int idx = tid + 256 * j;
        if (idx < n) pbf[(size_t)row * n + idx] = (ushort_t)f2bf(e[j] * inv);
    }
}

// ---------------------------------------------------------------------------
// PV MFMA: y[tok][dd] = P V. A = pbf [tok][m], B = vt [dd][m]. Scatter NCHW.
// CFG0: block 128tok x 128dd (wave 64x64); CFG1 (n=64): 64tok x 128dd;
// CFG2 (n=16): 32tok x 256dd (per-wave 64 dd).
// ---------------------------------------------------------------------------
template<int CFG>
__global__ __launch_bounds__(256) void pvm_kernel(
    const ushort_t* __restrict__ pbf, const ushort_t* __restrict__ vt,
    ushort_t* __restrict__ attn, int lg)
{
    const int outn = 128 >> lg, psz = 1 << lg;
    const int n = 4 * outn * outn;
    const int Dd = 32 << (2 * lg);
    const int scale = 6 - lg;
    const int b_ = blockIdx.z;
    const int tid = threadIdx.x, lane = tid & 63, wv = tid >> 6;
    const ushort_t* pb = pbf + (size_t)b_ * n * n;
    const ushort_t* vb = vt + (size_t)b_ * (size_t)Dd * n;
    constexpr int MF = (CFG == 0) ? 2 : 1;
    const int mb = (CFG == 0) ? blockIdx.y * 128 + (wv & 1) * 64
                 : (CFG == 1) ? (wv & 1) * 32 : 0;
    const int nb = (CFG == 0) ? blockIdx.x * 128 + (wv >> 1) * 64
                 : (CFG == 1) ? blockIdx.x * 128 + (wv >> 1) * 64
                 : blockIdx.x * 256 + wv * 64;
    const int koff = (lane >> 5) * 8;

    f32x16 acc[MF][2];
    #pragma unroll
    for (int i = 0; i < MF; ++i)
        #pragma unroll
        for (int j = 0; j < 2; ++j)
            #pragma unroll
            for (int k = 0; k < 16; ++k) acc[i][j][k] = 0.f;

    int mr[MF];
    #pragma unroll
    for (int i = 0; i < MF; ++i) {
        int r = mb + i * 32 + (lane & 31);
        if (CFG == 2 && r >= n) r = n - 1;
        mr[i] = r;
    }
    const int nr0 = nb + (lane & 31), nr1 = nr0 + 32;

    for (int k0 = 0; k0 < n; k0 += 16) {
        bf16x8 b0 = *(const bf16x8*)(vb + (size_t)nr0 * n + k0 + koff);
        bf16x8 b1 = *(const bf16x8*)(vb + (size_t)nr1 * n + k0 + koff);
        #pragma unroll
        for (int i = 0; i < MF; ++i) {
            bf16x8 a = *(const bf16x8*)(pb + (size_t)mr[i] * n + k0 + koff);
            acc[i][0] = __builtin_amdgcn_mfma_f32_32x32x16_bf16(a, b0, acc[i][0], 0, 0, 0);
            acc[i][1] = __builtin_amdgcn_mfma_f32_32x32x16_bf16(a, b1, acc[i][1], 0, 0, 0);
        }
    }

    const int lgo = 7 - lg;
    #pragma unroll
    for (int i = 0; i < MF; ++i)
        #pragma unroll
        for (int j = 0; j < 2; ++j)
            #pragma unroll
            for (int rg = 0; rg < 16; ++rg) {
                int tok = mb + i * 32 + (rg & 3) + 8 * (rg >> 2) + 4 * (lane >> 5);
                if (CFG == 2 && tok >= n) continue;
                int dd = nb + j * 32 + (lane & 31);
                int c_local = dd >> (2 * lg);
                int p2 = dd & (psz * psz - 1);
                int ph = p2 >> lg, pw = p2 & (psz - 1);
                int t_ = tok >> (2 * lgo);
                int rem = tok & ((1 << (2 * lgo)) - 1);
                int oh = rem >> lgo, ow = rem & (outn - 1);
                size_t off = (((size_t)(b_ * 4 + t_) * 128 + scale * 32 + c_local) * 128
                              + ((oh << lg) + ph)) * 128 + ((ow << lg) + pw);
                attn[off] = (ushort_t)f2bf(acc[i][j][rg]);
            }
}

// ---------------------------------------------------------------------------
// MFMA implicit-GEMM 3x3 conv (unchanged from r2).
// ---------------------------------------------------------------------------
template<int DIL, int MODE>
__global__ __launch_bounds__(256, 2) void conv3m_kernel(
    const ushort_t* __restrict__ in, const ushort_t* __restrict__ Wp,
    const float* __restrict__ bias, const float* __restrict__ res,
    float* __restrict__ outf, ushort_t* __restrict__ outb,
    const ushort_t* __restrict__ zp)
{
    constexpr int NSLOT = (DIL == 1) ? 4 : 6;
    __shared__ ushort_t lds[NSLOT * 144 * 32];
    const int h0 = blockIdx.x * 2, img = blockIdx.y;
    const int tid = threadIdx.x, lane = tid & 63, wv = tid >> 6;
    const int r = wv & 1;
    const int wco = (wv >> 1) * 64;
    const int imrow_out = h0 + r;

    f32x16 acc[4][2];
    #pragma unroll
    for (int tm = 0; tm < 4; ++tm)
        #pragma unroll
        for (int tn = 0; tn < 2; ++tn)
            #pragma unroll
            for (int k = 0; k < 16; ++k) acc[tm][tn][k] = 0.f;

    for (int cc = 0; cc < 4; ++cc) {
        const int cib = cc * 32;
        __syncthreads();
        for (int kb = wv; kb < NSLOT * 9; kb += 4) {
            int slot = kb / 9, px0 = (kb % 9) * 16;
            int px = px0 + (lane >> 2), chunk = lane & 3;
            int wc = px - DIL, ir = h0 - DIL + slot;
            const ushort_t* src;
            if (wc >= 0 && wc < 128 && ir >= 0 && ir < 128)
                src = in + (((size_t)(img * 128 + ir) * 128 + wc) * 128 + cib
                            + ((chunk ^ ((px >> 1) & 3)) << 3));
            else
                src = zp + lane * 8;
            async16(src, (char*)lds + kb * 1024);
        }
        asm volatile("s_waitcnt vmcnt(0)" ::: "memory");
        __syncthreads();
        for (int tap = 0; tap < 9; ++tap) {
            const int tr = tap / 3, tc = tap % 3;
            const int slot = r + tr * DIL;
            const ushort_t* sb = lds + slot * 4608;
            #pragma unroll
            for (int s = 0; s < 2; ++s) {
                const int fbase = ((cc * 9 + tap) * 2 + s) * 4 + (wco >> 5);
                bf16x8 a0 = *(const bf16x8*)(Wp + ((size_t)fbase * 64 + lane) * 8);
                bf16x8 a1 = *(const bf16x8*)(Wp + ((size_t)(fbase + 1) * 64 + lane) * 8);
                const int kch = s * 2 + (lane >> 5);
                bf16x8 b[4];
                #pragma unroll
                for (int tm = 0; tm < 4; ++tm) {
                    int px = tm * 32 + (lane & 31) + tc * DIL;
                    b[tm] = *(const bf16x8*)(sb + px * 32 + ((kch ^ ((px >> 1) & 3)) << 3));
                }
                #pragma unroll
                for (int tm = 0; tm < 4; ++tm) {
                    acc[tm][0] = __builtin_amdgcn_mfma_f32_32x32x16_bf16(a0, b[tm], acc[tm][0], 0, 0, 0);
                    acc[tm][1] = __builtin_amdgcn_mfma_f32_32x32x16_bf16(a1, b[tm], acc[tm][1], 0, 0, 0);
                }
            }
        }
    }
    #pragma unroll
    for (int tn = 0; tn < 2; ++tn) {
        #pragma unroll
        for (int rg = 0; rg < 16; ++rg) {
            int co = wco + tn * 32 + (rg & 3) + 8 * (rg >> 2) + 4 * (lane >> 5);
            float bb = bias[co];
            size_t rowbase = (((size_t)(img * 128 + co)) * 128 + imrow_out) * 128;
            #pragma unroll
            for (int tm = 0; tm < 4; ++tm) {
                int wcol = tm * 32 + (lane & 31);
                float v = acc[tm][tn][rg] + bb;
                v = (v >= 0.f) ? v : 0.2f * v;
                size_t idx = rowbase + wcol;
                if (MODE == 0)      outf[idx] = res[idx] + v;
                else if (MODE == 1) outb[idx] = (ushort_t)f2bf(v);
                else                outf[idx] = outf[idx] + v;
            }
        }
    }
}

// ---------------------------------------------------------------------------
extern "C" void kernel_launch(void* const* d_in, const int* in_sizes, int n_in,
                              void* d_out, int out_size, void* d_ws, size_t ws_size,
                              hipStream_t stream)
{
    const float* x   = (const float*)d_in[0];
    const float* Wq  = (const float*)d_in[1];
    const float* bq  = (const float*)d_in[2];
    const float* Wk  = (const float*)d_in[3];
    const float* bk  = (const float*)d_in[4];
    const float* Wv  = (const float*)d_in[5];
    const float* bv  = (const float*)d_in[6];
    const float* Wo  = (const float*)d_in[7];
    const float* bo  = (const float*)d_in[8];
    const float* Wf1 = (const float*)d_in[9];
    const float* bf1 = (const float*)d_in[10];
    const float* Wf2 = (const float*)d_in[11];
    const float* bf2 = (const float*)d_in[12];
    float* out = (float*)d_out;
    char* ws = (char*)d_ws;
    const size_t MB = 1048576ull;
    ushort_t* qw   = (ushort_t*)(ws);                 // 64 MB
    ushort_t* kw   = (ushort_t*)(ws + 64 * MB);       // 64 MB
    ushort_t* vw   = (ushort_t*)(ws + 128 * MB);      // 64 MB
    ushort_t* attn = (ushort_t*)(ws + 192 * MB);      // 64 MB (aliases x-NHWC, ff1)
    float*    sc   = (float*)   (ws + 256 * MB);      // 16 MB
    ushort_t* Wp   = (ushort_t*)(ws + 273 * MB);      // 864 KB
    ushort_t* Wqkv = (ushort_t*)(ws + 274 * MB);      // 96 KB
    ushort_t* zp   = (ushort_t*)(ws + 275 * MB);      // 1 KB zeros
    ushort_t* pbf  = (ushort_t*)(ws + 276 * MB);      // 8 MB
    ushort_t* vt   = (ushort_t*)(ws + 285 * MB);      // 16 MB
    ushort_t* nhwcx = attn;
    ushort_t* nhwc  = qw;
    ushort_t* ff1   = attn;

    hipMemsetAsync(zp, 0, 1024, stream);
    prepack_kernel<<<dim3(576, 3), 256, 0, stream>>>(Wo, Wf1, Wf2, Wp);
    prepack1_kernel<<<dim3(64, 3), 256, 0, stream>>>(Wq, Wk, Wv, Wqkv);

    // 1) x -> NHWC bf16, then q/k/v MFMA -> windowed layouts
    nchw2nhwc_kernel<1><<<dim3(128, 16), 256, 0, stream>>>(x, nhwcx);
    qkvm_kernel<<<dim3(64, 16, 3), 256, 0, stream>>>(nhwcx, Wqkv, bq, bk, bv, qw, kw, vw);

    // 2) per-scale attention: vtrans -> scores -> softmax -> pv
    // s0: n=16, Dd=131072
    vtrans_kernel<<<dim3(1024, 1, 4), 256, 0, stream>>>(vw + 0 * 8388608u, vt, 16, 131072);
    hipMemsetAsync(sc, 0, (size_t)4 * 16 * 16 * 4, stream);
    scoresm_kernel<2><<<dim3(1, 1, 256), 256, 0, stream>>>(qw, kw, sc, 6, 64);
    softmax_kernel<<<dim3(64), 256, 0, stream>>>(sc, pbf, 16);
    pvm_kernel<2><<<dim3(512, 1, 4), 256, 0, stream>>>(pbf, vt, attn, 6);
    // s1: n=64, Dd=32768
    vtrans_kernel<<<dim3(256, 1, 4), 256, 0, stream>>>(vw + 1 * 8388608u, vt, 64, 32768);
    hipMemsetAsync(sc, 0, (size_t)4 * 64 * 64 * 4, stream);
    scoresm_kernel<1><<<dim3(1, 1, 256), 256, 0, stream>>>(qw, kw, sc, 5, 64);
    softmax_kernel<<<dim3(256), 256, 0, stream>>>(sc, pbf, 64);
    pvm_kernel<1><<<dim3(256, 1, 4), 256, 0, stream>>>(pbf, vt, attn, 5);
    // s2: n=256, Dd=8192
    vtrans_kernel<<<dim3(64, 2, 4), 256, 0, stream>>>(vw + 2 * 8388608u, vt, 256, 8192);
    hipMemsetAsync(sc, 0, (size_t)4 * 256 * 256 * 4, stream);
    scoresm_kernel<0><<<dim3(2, 2, 64), 256, 0, stream>>>(qw, kw, sc, 4, 16);
    softmax_kernel<<<dim3(1024), 256, 0, stream>>>(sc, pbf, 256);
    pvm_kernel<0><<<dim3(64, 2, 4), 256, 0, stream>>>(pbf, vt, attn, 4);
    // s3: n=1024, Dd=2048
    vtrans_kernel<<<dim3(16, 8, 4), 256, 0, stream>>>(vw + 3 * 8388608u, vt, 1024, 2048);
    scoresm_kernel<0><<<dim3(8, 8, 4), 256, 0, stream>>>(qw, kw, sc, 3, 1);
    softmax_kernel<<<dim3(4096), 256, 0, stream>>>(sc, pbf, 1024);
    pvm_kernel<0><<<dim3(16, 8, 4), 256, 0, stream>>>(pbf, vt, attn, 3);

    // 3) conv path (unchanged)
    nchw2nhwc_kernel<0><<<dim3(128, 16), 256, 0, stream>>>(attn, nhwc);
    conv3m_kernel<1, 0><<<dim3(64, 16), 256, 0, stream>>>(nhwc, Wp, bo, x, out, nullptr, zp);
    nchw2nhwc_kernel<1><<<dim3(128, 16), 256, 0, stream>>>(out, nhwc);
    conv3m_kernel<2, 1><<<dim3(64, 16), 256, 0, stream>>>(nhwc, Wp + 147456, bf1, nullptr, nullptr, ff1, zp);
    nchw2nhwc_kernel<0><<<dim3(128, 16), 256, 0, stream>>>(ff1, nhwc);
    conv3m_kernel<1, 2><<<dim3(64, 16), 256, 0, stream>>>(nhwc, Wp + 2 * 147456, bf2, nullptr, out, nullptr, zp);
}